// Round 11
// baseline (367.897 us; speedup 1.0000x reference)
//
#include <hip/hip_runtime.h>
#include <hip/hip_bf16.h>

namespace {
constexpr int kB = 8;
constexpr int kC = 64;
constexpr int kH = 48;
constexpr int kW = 48;
constexpr int kS = kH * kW;          // 2304
constexpr float kEps = 1.1920929e-07f;
// 0.25 (1/sqrt(head_dim)) * log2(e): lets attention use raw v_exp_f32 (2^x)
constexpr float kQScale = 0.25f * 1.4426950408889634f;
constexpr int kGrid = 1024;          // exactly 4 blocks/CU -> all co-resident
}

typedef __attribute__((ext_vector_type(8))) short short8;   // 8 bf16 (4 VGPR)
typedef __attribute__((ext_vector_type(4))) float f32x4;

// fp32 -> bf16 (round-nearest-even), bit-level
__device__ __forceinline__ short f2bf(float x) {
  unsigned u = __float_as_uint(x);
  u += 0x7fffu + ((u >> 16) & 1u);
  return (short)(u >> 16);
}
__device__ __forceinline__ float bf2f(short s) {
  return __uint_as_float(((unsigned)(unsigned short)s) << 16);
}
__device__ __forceinline__ float fexp2(float x) {
  return __builtin_amdgcn_exp2f(x);   // v_exp_f32 (2^x)
}

// Device-scope grid barrier (plain launch; all kGrid blocks are co-resident
// by construction: LDS 40256B*4 <= 160KB, launch_bounds(256,4) caps VGPR).
// Release fence -> arrive -> spin -> acquire fence (Guideline 16 recipe).
__device__ __forceinline__ void gbar(int* c, int target) {
  __syncthreads();
  if (threadIdx.x == 0) {
    __threadfence();                               // release (cross-XCD)
    atomicAdd(c, 1);
    while (atomicAdd(c, 0) < target) __builtin_amdgcn_s_sleep(2);
    __threadfence();                               // acquire/invalidate
  }
  __syncthreads();
}

// attn main-loop macros
#define LOADT(K0, K1, V0, V1, V2, V3, JT)                                      \
  do {                                                                         \
    const short* kb_ = kbase + (size_t)(JT) * 4096;                            \
    const short* vb_ = vbase + (size_t)(JT) * 4096;                            \
    K0 = *reinterpret_cast<const short8*>(kb_);                                \
    K1 = *reinterpret_cast<const short8*>(kb_ + 512);                          \
    V0 = *reinterpret_cast<const short8*>(vb_);                                \
    V1 = *reinterpret_cast<const short8*>(vb_ + 512);                          \
    V2 = *reinterpret_cast<const short8*>(vb_ + 1024);                         \
    V3 = *reinterpret_cast<const short8*>(vb_ + 1536);                         \
  } while (0)

#define PHASE(K0, K1, V0, V1, V2, V3)                                          \
  do {                                                                         \
    _Pragma("unroll")                                                          \
    for (int hl = 0; hl < 2; ++hl) {                                           \
      f32x4 s0 = __builtin_amdgcn_mfma_f32_16x16x32_bf16(K0, qm[hl], zc, 0, 0, 0); \
      f32x4 s1 = __builtin_amdgcn_mfma_f32_16x16x32_bf16(K1, qm[hl], zc, 0, 0, 0); \
      float e0 = fexp2(s0[0]), e1 = fexp2(s0[1]);                              \
      float e2 = fexp2(s0[2]), e3 = fexp2(s0[3]);                              \
      float f0 = fexp2(s1[0]), f1 = fexp2(s1[1]);                              \
      float f2 = fexp2(s1[2]), f3 = fexp2(s1[3]);                              \
      union { __hip_bfloat162 h2[4]; short8 s8; } cv;                          \
      cv.h2[0] = __float22bfloat162_rn(make_float2(e0, e1));                   \
      cv.h2[1] = __float22bfloat162_rn(make_float2(e2, e3));                   \
      cv.h2[2] = __float22bfloat162_rn(make_float2(f0, f1));                   \
      cv.h2[3] = __float22bfloat162_rn(make_float2(f2, f3));                   \
      U[hl][0] = __builtin_amdgcn_mfma_f32_16x16x32_bf16(V0, cv.s8, U[hl][0], 0, 0, 0); \
      U[hl][1] = __builtin_amdgcn_mfma_f32_16x16x32_bf16(V1, cv.s8, U[hl][1], 0, 0, 0); \
      U[hl][2] = __builtin_amdgcn_mfma_f32_16x16x32_bf16(V2, cv.s8, U[hl][2], 0, 0, 0); \
      U[hl][3] = __builtin_amdgcn_mfma_f32_16x16x32_bf16(V3, cv.s8, U[hl][3], 0, 0, 0); \
      Ul[hl]   = __builtin_amdgcn_mfma_f32_16x16x32_bf16(af_l, cv.s8, Ul[hl], 0, 0, 0); \
    }                                                                          \
  } while (0)

// ---------------------------------------------------------------------------
// Single plain-launch kernel, 3 phases + 2 manual grid barriers.
// LDS union (40256 B): A: vt f32[16][260]@0 | B: Qs s16[164][72]@0,
// tile f32[64][65]@23616, ln s16[4][16][80]@23616 (aliases tile; tile dead
// after staging barrier) | C: pl@0, Li@512, slab@768.
// ---------------------------------------------------------------------------
__global__ __launch_bounds__(256, 4) void fused_all(
    const float* __restrict__ q, const float* __restrict__ k,
    const float* __restrict__ v, const float* __restrict__ wq,
    const float* __restrict__ wk, const float* __restrict__ conv_w,
    const float* __restrict__ nq_w, const float* __restrict__ nk_w,
    const float* __restrict__ bq, const float* __restrict__ bk,
    short* __restrict__ vq, short* __restrict__ qp, short* __restrict__ kq,
    short* __restrict__ wqb3, short* __restrict__ wkb3, short* __restrict__ wt3,
    float* __restrict__ out, int* cnt) {
  __shared__ __align__(16) char smem[40256];
  const int blk = blockIdx.x;
  const int t = threadIdx.x;
  const int ws = t >> 6;
  const int L = t & 63;
  const int quad = L >> 4;
  const int l16 = L & 15;
  const int tx = t & 63;
  const int ty = t >> 6;
  const short8 zero8 = {0, 0, 0, 0, 0, 0, 0, 0};

  // ====================== Phase A: prep (1040 units) ======================
  for (int u = blk; u < 1040; u += kGrid) {
    if (u < 288) {
      // v -> fragment-major vq, coalesced both directions (round-10 version)
      float (*vt)[260] = reinterpret_cast<float(*)[260]>(smem);
      const int b = u / 36;
      const int rem = u % 36;
      const int d = rem / 9;
      const int jg = rem % 9;
      const float* vb = v + ((size_t)(b * 64 + d * 16)) * kS + jg * 256;
#pragma unroll
      for (int p = 0; p < 4; ++p) {
        int row = p * 4 + ty;
        *reinterpret_cast<float4*>(&vt[row][tx * 4]) =
            *reinterpret_cast<const float4*>(vb + (size_t)row * kS + tx * 4);
      }
      __syncthreads();
      short* vqb = vq + (((size_t)(b * 72 + jg * 8) * 4 + d) * 64) * 8;
#pragma unroll
      for (int uu = 0; uu < 2; ++uu) {
        int g = uu * 256 + t;
        int jl = g >> 6;
        int Lq = g & 63;
        const float* src = &vt[Lq & 15][jl * 32 + (Lq >> 4) * 8];
        short8 o;
#pragma unroll
        for (int e = 0; e < 8; ++e) o[e] = f2bf(src[e]);
        *reinterpret_cast<short8*>(vqb + ((size_t)jl * 256 + Lq) * 8) = o;
      }
      __syncthreads();   // vt reuse safety for grid-stride second pass
    } else if (u < 464) {
      int idx = (u - 288) * 256 + t;           // < 45056
      if (idx < 4096) {
        int j = idx & 7, Lw = (idx >> 3) & 63, slab = idx >> 9;
        int nt = slab & 3, kh = slab >> 2;
        int e = nt * 16 + (Lw & 15), c = kh * 32 + (Lw >> 4) * 8 + j;
        wqb3[idx] = f2bf(wq[e * 64 + c]);
      } else if (idx < 8192) {
        int i2 = idx - 4096;
        int j = i2 & 7, Lw = (i2 >> 3) & 63, slab = i2 >> 9;
        int nt = slab & 3, kh = slab >> 2;
        int e = nt * 16 + (Lw & 15), c = kh * 32 + (Lw >> 4) * 8 + j;
        wkb3[i2] = f2bf(wk[e * 64 + c]);
      } else {
        int i3 = idx - 8192;   // < 36864
        int j = i3 & 7, Lw = (i3 >> 3) & 63, slab = i3 >> 9;
        int nt = slab & 3, kh = (slab >> 2) & 1, tap = slab >> 3;
        int co = nt * 16 + (Lw & 15), ci = kh * 32 + (Lw >> 4) * 8 + j;
        wt3[i3] = f2bf(conv_w[co * 576 + ci * 9 + tap]);
      }
    } else {
      // zero the output; 8 floats/thread, exact cover of 1,179,648
      size_t i = (size_t)(u - 464) * 256 + t;
      float4 z = make_float4(0.f, 0.f, 0.f, 0.f);
      *reinterpret_cast<float4*>(out + i * 8) = z;
      *reinterpret_cast<float4*>(out + i * 8 + 4) = z;
    }
  }

  gbar(cnt + 0, kGrid);

  // ====================== Phase B: q/k gemm (576 units) ===================
  if (blk < 576) {
    short (*Qs)[72] = reinterpret_cast<short(*)[72]>(smem);
    float (*tile)[65] = reinterpret_cast<float(*)[65]>(smem + 23616);
    short (*ln)[16][80] = reinterpret_cast<short(*)[16][80]>(smem + 23616);

    if (blk < 288) {
      // ---- q path ----
      const int b = blk / 36;
      const int S0 = (blk % 36) * 64;
      const int sBase = S0 + ws * 16;
      const int s = sBase + l16;
      const int h = s / kW, w = s % kW;

      const float* qb = q + (size_t)b * kC * kS;
#pragma unroll
      for (int p = 0; p < 3; ++p) {
        int scol = S0 - 49 + p * 64 + tx;
        scol = scol < 0 ? 0 : (scol >= kS ? kS - 1 : scol);
#pragma unroll
        for (int r = 0; r < 16; ++r) {
          int c = r * 4 + ty;
          tile[c][tx] = qb[(size_t)c * kS + scol];
        }
        __syncthreads();
#pragma unroll
        for (int r = 0; r < 16; ++r) {
          int j = r * 4 + ty;
          int srow = p * 64 + j;
          if (srow < 164) Qs[srow][tx] = f2bf(tile[tx][j]);
        }
        __syncthreads();
      }

      const int baseLocal = ws * 16 + l16 + 49;
      f32x4 acc[4] = {{0.f, 0.f, 0.f, 0.f}, {0.f, 0.f, 0.f, 0.f},
                      {0.f, 0.f, 0.f, 0.f}, {0.f, 0.f, 0.f, 0.f}};
#pragma unroll
      for (int tap = 0; tap < 9; ++tap) {
        const int dh = tap / 3 - 1, dw = tap % 3 - 1;
        const bool valid = (unsigned)(h + dh) < (unsigned)kH &&
                           (unsigned)(w + dw) < (unsigned)kW;
        const int local = baseLocal + dh * kW + dw;
#pragma unroll
        for (int kh = 0; kh < 2; ++kh) {
          short8 af = *reinterpret_cast<const short8*>(&Qs[local][kh * 32 + quad * 8]);
          af = valid ? af : zero8;
          const short* wb = wt3 + ((tap * 2 + kh) * 4) * 512 + L * 8;
#pragma unroll
          for (int nt = 0; nt < 4; ++nt) {
            short8 bf = *reinterpret_cast<const short8*>(wb + nt * 512);
            acc[nt] = __builtin_amdgcn_mfma_f32_16x16x32_bf16(af, bf, acc[nt], 0, 0, 0);
          }
        }
      }
      float rstd[4];
#pragma unroll
      for (int reg = 0; reg < 4; ++reg) {
        float pr = acc[0][reg] * acc[0][reg] + acc[1][reg] * acc[1][reg]
                 + acc[2][reg] * acc[2][reg] + acc[3][reg] * acc[3][reg];
        pr += __shfl_xor(pr, 1, 64);
        pr += __shfl_xor(pr, 2, 64);
        pr += __shfl_xor(pr, 4, 64);
        pr += __shfl_xor(pr, 8, 64);
        rstd[reg] = rsqrtf(pr * (1.0f / kC) + kEps);
      }
      // ln aliases tile: staging finished at the last __syncthreads above,
      // and no thread reads tile afterwards -> safe to overwrite.
      __syncthreads();
#pragma unroll
      for (int nt = 0; nt < 4; ++nt) {
        float g = nq_w[nt * 16 + l16];
#pragma unroll
        for (int reg = 0; reg < 4; ++reg) {
          ln[ws][quad * 4 + reg][nt * 16 + l16] = f2bf(acc[nt][reg] * rstd[reg] * g);
        }
      }
      __syncthreads();
      f32x4 acc2[4] = {{0.f, 0.f, 0.f, 0.f}, {0.f, 0.f, 0.f, 0.f},
                       {0.f, 0.f, 0.f, 0.f}, {0.f, 0.f, 0.f, 0.f}};
#pragma unroll
      for (int kh = 0; kh < 2; ++kh) {
        short8 af = *reinterpret_cast<const short8*>(&ln[ws][l16][kh * 32 + quad * 8]);
        const short* wb = wqb3 + (kh * 4) * 512 + L * 8;
#pragma unroll
        for (int nt = 0; nt < 4; ++nt) {
          short8 bf = *reinterpret_cast<const short8*>(wb + nt * 512);
          acc2[nt] = __builtin_amdgcn_mfma_f32_16x16x32_bf16(af, bf, acc2[nt], 0, 0, 0);
        }
      }
#pragma unroll
      for (int nt = 0; nt < 4; ++nt) {
        const int e = nt * 16 + l16;
        float bias = bq[e];
#pragma unroll
        for (int reg = 0; reg < 4; ++reg) {
          qp[((size_t)b * kS + sBase + quad * 4 + reg) * kC + e] =
              f2bf((acc2[nt][reg] + bias) * kQScale);
        }
      }
    } else {
      // ---- k path ----
      const int idx = blk - 288;
      const int b = idx / 36;
      const int S0 = (idx % 36) * 64;
      const int sBase = S0 + ws * 16;

      const float* kb = k + (size_t)b * kC * kS;
#pragma unroll
      for (int r = 0; r < 16; ++r) {
        int c = r * 4 + ty;
        tile[c][tx] = kb[(size_t)c * kS + S0 + tx];
      }
      __syncthreads();
#pragma unroll
      for (int r = 0; r < 16; ++r) {
        int j = r * 4 + ty;
        Qs[j][tx] = f2bf(tile[tx][j]);
      }
      __syncthreads();

      short8 af0 = *reinterpret_cast<const short8*>(&Qs[ws * 16 + l16][quad * 8]);
      short8 af1 = *reinterpret_cast<const short8*>(&Qs[ws * 16 + l16][32 + quad * 8]);

      float xs[16];
#pragma unroll
      for (int j = 0; j < 8; ++j) { xs[j] = bf2f(af0[j]); xs[8 + j] = bf2f(af1[j]); }
      float sum = 0.f;
#pragma unroll
      for (int j = 0; j < 16; ++j) sum = fmaf(xs[j], xs[j], sum);
      sum += __shfl_xor(sum, 16, 64);
      sum += __shfl_xor(sum, 32, 64);
      float rstd = rsqrtf(sum * (1.0f / kC) + kEps);

      const float* n0 = nk_w + quad * 8;
#pragma unroll
      for (int j = 0; j < 8; ++j) {
        af0[j] = f2bf(xs[j] * rstd * n0[j]);
        af1[j] = f2bf(xs[8 + j] * rstd * n0[32 + j]);
      }

      f32x4 acc[4] = {{0.f, 0.f, 0.f, 0.f}, {0.f, 0.f, 0.f, 0.f},
                      {0.f, 0.f, 0.f, 0.f}, {0.f, 0.f, 0.f, 0.f}};
#pragma unroll
      for (int nt = 0; nt < 4; ++nt) {
        short8 bf0 = *reinterpret_cast<const short8*>(
            wkb3 + (0 * 4 + nt) * 512 + L * 8);
        short8 bf1 = *reinterpret_cast<const short8*>(
            wkb3 + (1 * 4 + nt) * 512 + L * 8);
        acc[nt] = __builtin_amdgcn_mfma_f32_16x16x32_bf16(af0, bf0, acc[nt], 0, 0, 0);
        acc[nt] = __builtin_amdgcn_mfma_f32_16x16x32_bf16(af1, bf1, acc[nt], 0, 0, 0);
      }
      short* kqb = kq + (size_t)b * 147456;   // 72 * 2048 shorts per batch
#pragma unroll
      for (int nt = 0; nt < 4; ++nt) {
        const int hp = nt >> 1;
        const int quadp = ((nt & 1) << 1) | (l16 >> 3);
        const int elem = l16 & 7;
        float bias = bk[nt * 16 + l16];
#pragma unroll
        for (int reg = 0; reg < 4; ++reg) {
          int s = sBase + quad * 4 + reg;
          int jseg = s >> 5, jrow = s & 31;
          int c = (jrow >> 2) & 1;
          int l16p = ((jrow >> 3) << 2) | (jrow & 3);
          kqb[((((size_t)jseg * 2 + hp) * 2 + c) * 64 + quadp * 16 + l16p) * 8 + elem] =
              f2bf(acc[nt][reg] + bias);
        }
      }
    }
  }

  gbar(cnt + 1, kGrid);

  // ====================== Phase C: attention (1152 units) =================
  {
    float (*pl)[16][2] = reinterpret_cast<float(*)[16][2]>(smem);
    float (*Li)[2] = reinterpret_cast<float(*)[2]>(smem + 512);
    float (*slab)[66] = reinterpret_cast<float(*)[66]>(smem + 768);

    for (int rep = 0; rep < 2; ++rep) {
      if (rep == 1 && blk >= 128) break;
      const int unit = blk + rep * kGrid;

      const int b = unit & 7;
      const int idx = unit >> 3;       // 0..143
      const int hp = idx & 1;
      const int i0 = (idx >> 1) * 32;
      const int isub = ws & 1;
      const int jhalf = ws >> 1;

      const f32x4 zc = {0.f, 0.f, 0.f, 0.f};
      const short8 z8 = {0, 0, 0, 0, 0, 0, 0, 0};
      const short ob = (short)0x3F80;   // bf16 1.0
      const short8 ones8 = {ob, ob, ob, ob, ob, ob, ob, ob};
      const short8 af_l = (l16 == 0) ? ones8 : z8;

      const short* qrow = qp + ((size_t)b * kS + i0 + isub * 16 + l16) * kC + hp * 32;
      const short8 qw = *reinterpret_cast<const short8*>(qrow + quad * 8);
      const bool lo = quad < 2;
      const short8 qm[2] = {lo ? qw : z8, lo ? z8 : qw};

      const short* kbase =
          kq + (((size_t)(b * 72 + jhalf) * 2 + hp) * 2 * 64 + L) * 8;
      const short* vbase = vq + ((size_t)(b * 72 + jhalf) * 4 * 64 + L) * 8;

      f32x4 U[2][4];
#pragma unroll
      for (int hl = 0; hl < 2; ++hl)
#pragma unroll
        for (int d = 0; d < 4; ++d) U[hl][d] = zc;
      f32x4 Ul[2] = {zc, zc};

      short8 ka0, ka1, va0, va1, va2, va3;
      short8 kb0, kb1, vb0, vb1, vb2, vb3;
      LOADT(ka0, ka1, va0, va1, va2, va3, 0);
      LOADT(kb0, kb1, vb0, vb1, vb2, vb3, 1);

      for (int jt = 0; jt < 34; jt += 2) {
        PHASE(ka0, ka1, va0, va1, va2, va3);
        LOADT(ka0, ka1, va0, va1, va2, va3, jt + 2);
        PHASE(kb0, kb1, vb0, vb1, vb2, vb3);
        LOADT(kb0, kb1, vb0, vb1, vb2, vb3, jt + 3);
      }
      PHASE(ka0, ka1, va0, va1, va2, va3);   // jt = 34
      PHASE(kb0, kb1, vb0, vb1, vb2, vb3);   // jt = 35

      // ---- epilogue ----
      if (quad == 0) {
#pragma unroll
        for (int hl = 0; hl < 2; ++hl) pl[ws][l16][hl] = Ul[hl][0];
      }
      __syncthreads();
      if (t < 64) {
        const int i = t >> 1, h2 = t & 1;
        Li[i][h2] = 0.25f / (pl[i >> 4][i & 15][h2] + pl[(i >> 4) + 2][i & 15][h2]);
      }
      __syncthreads();
      float c2[2];
#pragma unroll
      for (int hl = 0; hl < 2; ++hl) c2[hl] = Li[isub * 16 + l16][hl];

#pragma unroll
      for (int d = 0; d < 4; ++d) {
        if (jhalf == 1) {
#pragma unroll
          for (int hl = 0; hl < 2; ++hl)
#pragma unroll
            for (int reg = 0; reg < 4; ++reg)
              slab[(isub * 2 + hl) * 4 + reg][L] = U[hl][d][reg];
        }
        __syncthreads();
        if (jhalf == 0) {
          float of[4] = {0.f, 0.f, 0.f, 0.f};
#pragma unroll
          for (int hl = 0; hl < 2; ++hl) {
#pragma unroll
            for (int reg = 0; reg < 4; ++reg) {
              float tot = U[hl][d][reg] + slab[(isub * 2 + hl) * 4 + reg][L];
              of[reg] += tot * c2[hl];
            }
          }
          float* op = out + ((size_t)b * kS + i0 + isub * 16 + l16) * kC + d * 16 + quad * 4;
#pragma unroll
          for (int reg = 0; reg < 4; ++reg) atomicAdd(op + reg, of[reg]);
        }
        __syncthreads();
      }
    }
  }
}

// ---------------------------------------------------------------------------
extern "C" void kernel_launch(void* const* d_in, const int* in_sizes, int n_in,
                              void* d_out, int out_size, void* d_ws, size_t ws_size,
                              hipStream_t stream) {
  const float* q      = (const float*)d_in[0];
  const float* k      = (const float*)d_in[1];
  const float* v      = (const float*)d_in[2];
  const float* conv_w = (const float*)d_in[3];
  const float* nq_w   = (const float*)d_in[4];
  const float* nk_w   = (const float*)d_in[5];
  const float* wq     = (const float*)d_in[6];
  const float* bq     = (const float*)d_in[7];
  const float* wk     = (const float*)d_in[8];
  const float* bk     = (const float*)d_in[9];
  float* out = (float*)d_out;

  const size_t N = (size_t)kB * kS * kC;   // 1,179,648
  short* vq   = (short*)d_ws;     // bf16 fragment-major V
  short* qp   = vq + N;           // bf16 [b][s][64], pre-scaled by 0.25*log2(e)
  short* kq   = qp + N;           // bf16 fragment-major K-proj
  short* wqb3 = kq + N;           // frag-major bf16
  short* wkb3 = wqb3 + 4096;
  short* wt3  = wkb3 + 4096;      // frag-major bf16 [72 slabs][512]
  int*   cnt  = (int*)(wt3 + 36864);   // 2 barrier counters (8 B, 16-aligned)

  hipMemsetAsync(cnt, 0, 2 * sizeof(int), stream);
  fused_all<<<kGrid, 256, 0, stream>>>(q, k, v, wq, wk, conv_w,
                                       nq_w, nk_w, bq, bk,
                                       vq, qp, kq, wqb3, wkb3, wt3,
                                       out, cnt);
}

// Round 12
// 145.149 us; speedup vs baseline: 2.5346x; 2.5346x over previous
//
#include <hip/hip_runtime.h>
#include <hip/hip_bf16.h>

namespace {
constexpr int kB = 8;
constexpr int kC = 64;
constexpr int kH = 48;
constexpr int kW = 48;
constexpr int kS = kH * kW;          // 2304
constexpr float kEps = 1.1920929e-07f;
// 0.25 (1/sqrt(head_dim)) * log2(e): lets attention use raw v_exp_f32 (2^x)
constexpr float kQScale = 0.25f * 1.4426950408889634f;
}

typedef __attribute__((ext_vector_type(8))) short short8;   // 8 bf16 (4 VGPR)
typedef __attribute__((ext_vector_type(4))) float f32x4;

// fp32 -> bf16 (round-nearest-even), bit-level
__device__ __forceinline__ short f2bf(float x) {
  unsigned u = __float_as_uint(x);
  u += 0x7fffu + ((u >> 16) & 1u);
  return (short)(u >> 16);
}
__device__ __forceinline__ float bf2f(short s) {
  return __uint_as_float(((unsigned)(unsigned short)s) << 16);
}
__device__ __forceinline__ float fexp2(float x) {
  return __builtin_amdgcn_exp2f(x);   // v_exp_f32 (2^x)
}

// ---------------------------------------------------------------------------
// D1: prep_lite (round-10 version: coalesced v via LDS transpose tile).
// grid 1040: [0,288) v | [288,464) weights | [464,1040) zero out.
// ---------------------------------------------------------------------------
__global__ __launch_bounds__(256) void prep_lite(
    const float* __restrict__ v, const float* __restrict__ wq,
    const float* __restrict__ wk, const float* __restrict__ conv_w,
    short* __restrict__ vq, short* __restrict__ wqb3, short* __restrict__ wkb3,
    short* __restrict__ wt3, float* __restrict__ out) {
  __shared__ float vt[16][260];   // +4 pad: LDS read aliasing <= 2-way (free)
  const int blk = blockIdx.x;
  const int t = threadIdx.x;
  if (blk < 288) {
    // ---- v -> fragment-major vq, coalesced both directions ----
    const int b = blk / 36;
    const int rem = blk % 36;
    const int d = rem / 9;          // channel group d*16..+15
    const int jg = rem % 9;         // jseg group jg*8..+7 (s cols jg*256..+255)
    const float* vb = v + ((size_t)(b * 64 + d * 16)) * kS + jg * 256;
#pragma unroll
    for (int p = 0; p < 4; ++p) {
      int row = p * 4 + (t >> 6);
      int col4 = t & 63;
      *reinterpret_cast<float4*>(&vt[row][col4 * 4]) =
          *reinterpret_cast<const float4*>(vb + (size_t)row * kS + col4 * 4);
    }
    __syncthreads();
    short* vqb = vq + (((size_t)(b * 72 + jg * 8) * 4 + d) * 64) * 8;
#pragma unroll
    for (int uu = 0; uu < 2; ++uu) {
      int u = uu * 256 + t;
      int jl = u >> 6;              // 0..7 (local jseg)
      int Lq = u & 63;
      const float* src = &vt[Lq & 15][jl * 32 + (Lq >> 4) * 8];
      short8 o;
#pragma unroll
      for (int e = 0; e < 8; ++e) o[e] = f2bf(src[e]);
      *reinterpret_cast<short8*>(vqb + ((size_t)jl * 256 + Lq) * 8) = o;
    }
  } else if (blk < 464) {
    int idx = (blk - 288) * 256 + t;           // < 45056
    if (idx < 4096) {
      int j = idx & 7, Lw = (idx >> 3) & 63, slab = idx >> 9;
      int nt = slab & 3, kh = slab >> 2;
      int e = nt * 16 + (Lw & 15), c = kh * 32 + (Lw >> 4) * 8 + j;
      wqb3[idx] = f2bf(wq[e * 64 + c]);
    } else if (idx < 8192) {
      int i2 = idx - 4096;
      int j = i2 & 7, Lw = (i2 >> 3) & 63, slab = i2 >> 9;
      int nt = slab & 3, kh = slab >> 2;
      int e = nt * 16 + (Lw & 15), c = kh * 32 + (Lw >> 4) * 8 + j;
      wkb3[i2] = f2bf(wk[e * 64 + c]);
    } else {
      int i3 = idx - 8192;   // < 36864
      int j = i3 & 7, Lw = (i3 >> 3) & 63, slab = i3 >> 9;   // 0..71
      int nt = slab & 3, kh = (slab >> 2) & 1, tap = slab >> 3;
      int co = nt * 16 + (Lw & 15), ci = kh * 32 + (Lw >> 4) * 8 + j;
      wt3[i3] = f2bf(conv_w[co * 576 + ci * 9 + tap]);
    }
  } else {
    // zero the output (replaces hipMemsetAsync); 8 floats/thread, exact cover
    size_t i = (size_t)(blk - 464) * 256 + t;
    float4 z = make_float4(0.f, 0.f, 0.f, 0.f);
    *reinterpret_cast<float4*>(out + i * 8) = z;
    *reinterpret_cast<float4*>(out + i * 8 + 4) = z;
  }
}

// ---------------------------------------------------------------------------
// D2: q/k projection GEMMs. ONE change vs round 10: the q-path's 3 staging
// passes no longer serialize 3 cold-HBM round trips (load->sync->convert->
// sync, x3 ~= 3x900cyc exposed at 2.25 blk/CU). All 48 per-thread loads are
// issued UP FRONT into registers (one round trip); the per-pass LDS
// shuffle+convert then overlaps the remaining loads' latency. +48 VGPR is
// free here (kernel is grid-limited, not VGPR-limited). Math identical.
// ---------------------------------------------------------------------------
__global__ __launch_bounds__(256) void qk_gemm_t(
    const float* __restrict__ q, const float* __restrict__ k,
    const short* __restrict__ wt3, const short* __restrict__ wqb3,
    const short* __restrict__ wkb3,
    const float* __restrict__ nq_w, const float* __restrict__ nk_w,
    const float* __restrict__ bq, const float* __restrict__ bk,
    short* __restrict__ qp, short* __restrict__ kq) {
  __shared__ __align__(16) short Qs[164][72];   // q: halo tile / k: 64-row tile
  __shared__ __align__(16) short ln[4][16][80];
  __shared__ float tile[64][65];                // fp32 transpose staging
  const int blk = blockIdx.x;
  const int t = threadIdx.x;
  const int ws = t >> 6;
  const int L = t & 63;
  const int quad = L >> 4;
  const int l16 = L & 15;
  const int tx = t & 63;
  const int ty = t >> 6;
  const short8 zero8 = {0, 0, 0, 0, 0, 0, 0, 0};

  if (blk < 288) {
    // ---- q path ----
    const int b = blk / 36;
    const int S0 = (blk % 36) * 64;
    const int sBase = S0 + ws * 16;
    const int s = sBase + l16;
    const int h = s / kW, w = s % kW;

    // Stage halo rows S0-49 .. S0+114 (clamped): issue ALL 48 loads first
    // (one HBM round trip), then run the 3 LDS passes.
    const float* qb = q + (size_t)b * kC * kS;
    float rg[48];
#pragma unroll
    for (int p = 0; p < 3; ++p) {
      int scol = S0 - 49 + p * 64 + tx;
      scol = scol < 0 ? 0 : (scol >= kS ? kS - 1 : scol);
#pragma unroll
      for (int r = 0; r < 16; ++r) {
        int c = r * 4 + ty;
        rg[p * 16 + r] = qb[(size_t)c * kS + scol];
      }
    }
#pragma unroll
    for (int p = 0; p < 3; ++p) {
#pragma unroll
      for (int r = 0; r < 16; ++r) {
        int c = r * 4 + ty;
        tile[c][tx] = rg[p * 16 + r];
      }
      __syncthreads();
#pragma unroll
      for (int r = 0; r < 16; ++r) {
        int j = r * 4 + ty;
        int srow = p * 64 + j;
        if (srow < 164) Qs[srow][tx] = f2bf(tile[tx][j]);
      }
      __syncthreads();
    }

    const int baseLocal = ws * 16 + l16 + 49;
    f32x4 acc[4] = {{0.f, 0.f, 0.f, 0.f}, {0.f, 0.f, 0.f, 0.f},
                    {0.f, 0.f, 0.f, 0.f}, {0.f, 0.f, 0.f, 0.f}};
#pragma unroll
    for (int tap = 0; tap < 9; ++tap) {
      const int dh = tap / 3 - 1, dw = tap % 3 - 1;
      const bool valid = (unsigned)(h + dh) < (unsigned)kH &&
                         (unsigned)(w + dw) < (unsigned)kW;
      const int local = baseLocal + dh * kW + dw;
#pragma unroll
      for (int kh = 0; kh < 2; ++kh) {
        short8 af = *reinterpret_cast<const short8*>(&Qs[local][kh * 32 + quad * 8]);
        af = valid ? af : zero8;
        const short* wb = wt3 + ((tap * 2 + kh) * 4) * 512 + L * 8;
#pragma unroll
        for (int nt = 0; nt < 4; ++nt) {
          short8 bf = *reinterpret_cast<const short8*>(wb + nt * 512);  // coalesced
          acc[nt] = __builtin_amdgcn_mfma_f32_16x16x32_bf16(af, bf, acc[nt], 0, 0, 0);
        }
      }
    }
    float rstd[4];
#pragma unroll
    for (int reg = 0; reg < 4; ++reg) {
      float pr = acc[0][reg] * acc[0][reg] + acc[1][reg] * acc[1][reg]
               + acc[2][reg] * acc[2][reg] + acc[3][reg] * acc[3][reg];
      pr += __shfl_xor(pr, 1, 64);
      pr += __shfl_xor(pr, 2, 64);
      pr += __shfl_xor(pr, 4, 64);
      pr += __shfl_xor(pr, 8, 64);
      rstd[reg] = rsqrtf(pr * (1.0f / kC) + kEps);
    }
#pragma unroll
    for (int nt = 0; nt < 4; ++nt) {
      float g = nq_w[nt * 16 + l16];
#pragma unroll
      for (int reg = 0; reg < 4; ++reg) {
        ln[ws][quad * 4 + reg][nt * 16 + l16] = f2bf(acc[nt][reg] * rstd[reg] * g);
      }
    }
    __syncthreads();
    f32x4 acc2[4] = {{0.f, 0.f, 0.f, 0.f}, {0.f, 0.f, 0.f, 0.f},
                     {0.f, 0.f, 0.f, 0.f}, {0.f, 0.f, 0.f, 0.f}};
#pragma unroll
    for (int kh = 0; kh < 2; ++kh) {
      short8 af = *reinterpret_cast<const short8*>(&ln[ws][l16][kh * 32 + quad * 8]);
      const short* wb = wqb3 + (kh * 4) * 512 + L * 8;
#pragma unroll
      for (int nt = 0; nt < 4; ++nt) {
        short8 bf = *reinterpret_cast<const short8*>(wb + nt * 512);   // coalesced
        acc2[nt] = __builtin_amdgcn_mfma_f32_16x16x32_bf16(af, bf, acc2[nt], 0, 0, 0);
      }
    }
#pragma unroll
    for (int nt = 0; nt < 4; ++nt) {
      const int e = nt * 16 + l16;
      float bias = bq[e];
#pragma unroll
      for (int reg = 0; reg < 4; ++reg) {
        qp[((size_t)b * kS + sBase + quad * 4 + reg) * kC + e] =
            f2bf((acc2[nt][reg] + bias) * kQScale);
      }
    }
  } else {
    // ---- k path ----
    const int idx = blk - 288;
    const int b = idx / 36;
    const int S0 = (idx % 36) * 64;
    const int sBase = S0 + ws * 16;

    // stage 64 rows S0..S0+63 (single pass)
    const float* kb = k + (size_t)b * kC * kS;
#pragma unroll
    for (int r = 0; r < 16; ++r) {
      int c = r * 4 + ty;
      tile[c][tx] = kb[(size_t)c * kS + S0 + tx];
    }
    __syncthreads();
#pragma unroll
    for (int r = 0; r < 16; ++r) {
      int j = r * 4 + ty;
      Qs[j][tx] = f2bf(tile[tx][j]);
    }
    __syncthreads();

    short8 af0 = *reinterpret_cast<const short8*>(&Qs[ws * 16 + l16][quad * 8]);
    short8 af1 = *reinterpret_cast<const short8*>(&Qs[ws * 16 + l16][32 + quad * 8]);

    float xs[16];
#pragma unroll
    for (int j = 0; j < 8; ++j) { xs[j] = bf2f(af0[j]); xs[8 + j] = bf2f(af1[j]); }
    float sum = 0.f;
#pragma unroll
    for (int j = 0; j < 16; ++j) sum = fmaf(xs[j], xs[j], sum);
    sum += __shfl_xor(sum, 16, 64);
    sum += __shfl_xor(sum, 32, 64);
    float rstd = rsqrtf(sum * (1.0f / kC) + kEps);

    const float* n0 = nk_w + quad * 8;
#pragma unroll
    for (int j = 0; j < 8; ++j) {
      af0[j] = f2bf(xs[j] * rstd * n0[j]);
      af1[j] = f2bf(xs[8 + j] * rstd * n0[32 + j]);
    }

    f32x4 acc[4] = {{0.f, 0.f, 0.f, 0.f}, {0.f, 0.f, 0.f, 0.f},
                    {0.f, 0.f, 0.f, 0.f}, {0.f, 0.f, 0.f, 0.f}};
#pragma unroll
    for (int nt = 0; nt < 4; ++nt) {
      short8 bf0 = *reinterpret_cast<const short8*>(
          wkb3 + (0 * 4 + nt) * 512 + L * 8);
      short8 bf1 = *reinterpret_cast<const short8*>(
          wkb3 + (1 * 4 + nt) * 512 + L * 8);
      acc[nt] = __builtin_amdgcn_mfma_f32_16x16x32_bf16(af0, bf0, acc[nt], 0, 0, 0);
      acc[nt] = __builtin_amdgcn_mfma_f32_16x16x32_bf16(af1, bf1, acc[nt], 0, 0, 0);
    }
    // fragment-major store
    short* kqb = kq + (size_t)b * 147456;   // 72 * 2048 shorts per batch
#pragma unroll
    for (int nt = 0; nt < 4; ++nt) {
      const int hp = nt >> 1;
      const int quadp = ((nt & 1) << 1) | (l16 >> 3);
      const int elem = l16 & 7;
      float bias = bk[nt * 16 + l16];
#pragma unroll
      for (int reg = 0; reg < 4; ++reg) {
        int s = sBase + quad * 4 + reg;
        int jseg = s >> 5, jrow = s & 31;
        int c = (jrow >> 2) & 1;
        int l16p = ((jrow >> 3) << 2) | (jrow & 3);
        kqb[((((size_t)jseg * 2 + hp) * 2 + c) * 64 + quadp * 16 + l16p) * 8 + elem] =
            f2bf(acc[nt][reg] + bias);
      }
    }
  }
}

// ---------------------------------------------------------------------------
// D3: flash attention -- EXACT round-6 version (best measured: 57.3 us).
// Register-direct fragment-major, ones-row-MFMA denominator, 2-deep named
// register prefetch, grid 1152, __launch_bounds__(256,4).
// ---------------------------------------------------------------------------
#define LOADT(K0, K1, V0, V1, V2, V3, JT)                                      \
  do {                                                                         \
    const short* kb_ = kbase + (size_t)(JT) * 4096;                            \
    const short* vb_ = vbase + (size_t)(JT) * 4096;                            \
    K0 = *reinterpret_cast<const short8*>(kb_);                                \
    K1 = *reinterpret_cast<const short8*>(kb_ + 512);                          \
    V0 = *reinterpret_cast<const short8*>(vb_);                                \
    V1 = *reinterpret_cast<const short8*>(vb_ + 512);                          \
    V2 = *reinterpret_cast<const short8*>(vb_ + 1024);                         \
    V3 = *reinterpret_cast<const short8*>(vb_ + 1536);                         \
  } while (0)

#define PHASE(K0, K1, V0, V1, V2, V3)                                          \
  do {                                                                         \
    _Pragma("unroll")                                                          \
    for (int hl = 0; hl < 2; ++hl) {                                           \
      f32x4 s0 = __builtin_amdgcn_mfma_f32_16x16x32_bf16(K0, qm[hl], zc, 0, 0, 0); \
      f32x4 s1 = __builtin_amdgcn_mfma_f32_16x16x32_bf16(K1, qm[hl], zc, 0, 0, 0); \
      float e0 = fexp2(s0[0]), e1 = fexp2(s0[1]);                              \
      float e2 = fexp2(s0[2]), e3 = fexp2(s0[3]);                              \
      float f0 = fexp2(s1[0]), f1 = fexp2(s1[1]);                              \
      float f2 = fexp2(s1[2]), f3 = fexp2(s1[3]);                              \
      union { __hip_bfloat162 h2[4]; short8 s8; } cv;                          \
      cv.h2[0] = __float22bfloat162_rn(make_float2(e0, e1));                   \
      cv.h2[1] = __float22bfloat162_rn(make_float2(e2, e3));                   \
      cv.h2[2] = __float22bfloat162_rn(make_float2(f0, f1));                   \
      cv.h2[3] = __float22bfloat162_rn(make_float2(f2, f3));                   \
      U[hl][0] = __builtin_amdgcn_mfma_f32_16x16x32_bf16(V0, cv.s8, U[hl][0], 0, 0, 0); \
      U[hl][1] = __builtin_amdgcn_mfma_f32_16x16x32_bf16(V1, cv.s8, U[hl][1], 0, 0, 0); \
      U[hl][2] = __builtin_amdgcn_mfma_f32_16x16x32_bf16(V2, cv.s8, U[hl][2], 0, 0, 0); \
      U[hl][3] = __builtin_amdgcn_mfma_f32_16x16x32_bf16(V3, cv.s8, U[hl][3], 0, 0, 0); \
      Ul[hl]   = __builtin_amdgcn_mfma_f32_16x16x32_bf16(af_l, cv.s8, Ul[hl], 0, 0, 0); \
    }                                                                          \
  } while (0)

__global__ __launch_bounds__(256, 4) void attn_flash(
    const short* __restrict__ qp, const short* __restrict__ kq,
    const short* __restrict__ vq, float* __restrict__ out) {
  __shared__ float pl[4][16][2];            // [ws][i16][hl]
  __shared__ float Li[32][2];               // 0.25 / l
  __shared__ __align__(16) float slab[16][66];

  const int blk = blockIdx.x;
  const int b = blk & 7;           // low bits -> all of batch b on one XCD (L2 fit)
  const int idx = blk >> 3;        // 0..143
  const int hp = idx & 1;          // head pair: heads 2hp, 2hp+1
  const int i0 = (idx >> 1) * 32;
  const int t = threadIdx.x;
  const int ws = t >> 6;
  const int isub = ws & 1;
  const int jhalf = ws >> 1;
  const int L = t & 63;
  const int quad = L >> 4;
  const int l16 = L & 15;

  const f32x4 zc = {0.f, 0.f, 0.f, 0.f};
  const short8 z8 = {0, 0, 0, 0, 0, 0, 0, 0};
  const short ob = (short)0x3F80;   // bf16 1.0
  const short8 ones8 = {ob, ob, ob, ob, ob, ob, ob, ob};
  // ones-row A-frag: A[0][k]=1, A[r>0][k]=0 -> lanes with l16==0 hold ones.
  const short8 af_l = (l16 == 0) ? ones8 : z8;

  // Q window (B operand, K=32 = this head pair's d window)
  const short* qrow = qp + ((size_t)b * kS + i0 + isub * 16 + l16) * kC + hp * 32;
  const short8 qw = *reinterpret_cast<const short8*>(qrow + quad * 8);
  const bool lo = quad < 2;
  const short8 qm[2] = {lo ? qw : z8, lo ? z8 : qw};   // local heads 0,1 of the pair

  // Fragment-major bases: every load below is base + (lane)*16B, coalesced.
  const short* kbase =
      kq + (((size_t)(b * 72 + jhalf) * 2 + hp) * 2 * 64 + L) * 8;
  const short* vbase = vq + ((size_t)(b * 72 + jhalf) * 4 * 64 + L) * 8;

  f32x4 U[2][4];   // [hl][dtile]: lane holds d=dtile*16+quad*4+reg, i=l16
#pragma unroll
  for (int hl = 0; hl < 2; ++hl)
#pragma unroll
    for (int d = 0; d < 4; ++d) U[hl][d] = zc;
  f32x4 Ul[2] = {zc, zc};   // denominator: quad0/reg0 lane l16 holds l_i

  // 2-deep prefetch: tiles jt and jt+1 in named register buffers.
  short8 ka0, ka1, va0, va1, va2, va3;
  short8 kb0, kb1, vb0, vb1, vb2, vb3;
  LOADT(ka0, ka1, va0, va1, va2, va3, 0);
  LOADT(kb0, kb1, vb0, vb1, vb2, vb3, 1);

  for (int jt = 0; jt < 34; jt += 2) {
    PHASE(ka0, ka1, va0, va1, va2, va3);
    LOADT(ka0, ka1, va0, va1, va2, va3, jt + 2);
    PHASE(kb0, kb1, vb0, vb1, vb2, vb3);
    LOADT(kb0, kb1, vb0, vb1, vb2, vb3, jt + 3);
  }
  PHASE(ka0, ka1, va0, va1, va2, va3);   // jt = 34
  PHASE(kb0, kb1, vb0, vb1, vb2, vb3);   // jt = 35

  // ---- epilogue (first barrier re-syncs the free-running waves) ----
  if (quad == 0) {
#pragma unroll
    for (int hl = 0; hl < 2; ++hl) pl[ws][l16][hl] = Ul[hl][0];
  }
  __syncthreads();
  if (t < 64) {
    const int i = t >> 1, h2 = t & 1;    // i 0..31 (local sub-row)
    Li[i][h2] = 0.25f / (pl[i >> 4][i & 15][h2] + pl[(i >> 4) + 2][i & 15][h2]);
  }
  __syncthreads();
  float c2[2];
#pragma unroll
  for (int hl = 0; hl < 2; ++hl) c2[hl] = Li[isub * 16 + l16][hl];

  // jhalf-pair reduce, one d-tile per phase
#pragma unroll
  for (int d = 0; d < 4; ++d) {
    if (jhalf == 1) {
#pragma unroll
      for (int hl = 0; hl < 2; ++hl)
#pragma unroll
        for (int reg = 0; reg < 4; ++reg)
          slab[(isub * 2 + hl) * 4 + reg][L] = U[hl][d][reg];
    }
    __syncthreads();
    if (jhalf == 0) {
      float of[4] = {0.f, 0.f, 0.f, 0.f};
#pragma unroll
      for (int hl = 0; hl < 2; ++hl) {
#pragma unroll
        for (int reg = 0; reg < 4; ++reg) {
          float tot = U[hl][d][reg] + slab[(isub * 2 + hl) * 4 + reg][L];
          of[reg] += tot * c2[hl];
        }
      }
      float* op = out + ((size_t)b * kS + i0 + isub * 16 + l16) * kC + d * 16 + quad * 4;
#pragma unroll
      for (int reg = 0; reg < 4; ++reg) atomicAdd(op + reg, of[reg]);
    }
    __syncthreads();
  }
}

// ---------------------------------------------------------------------------
extern "C" void kernel_launch(void* const* d_in, const int* in_sizes, int n_in,
                              void* d_out, int out_size, void* d_ws, size_t ws_size,
                              hipStream_t stream) {
  const float* q      = (const float*)d_in[0];
  const float* k      = (const float*)d_in[1];
  const float* v      = (const float*)d_in[2];
  const float* conv_w = (const float*)d_in[3];
  const float* nq_w   = (const float*)d_in[4];
  const float* nk_w   = (const float*)d_in[5];
  const float* wq     = (const float*)d_in[6];
  const float* bq     = (const float*)d_in[7];
  const float* wk     = (const float*)d_in[8];
  const float* bk     = (const float*)d_in[9];
  float* out = (float*)d_out;

  const size_t N = (size_t)kB * kS * kC;   // 1,179,648
  short* vq   = (short*)d_ws;     // bf16 fragment-major V
  short* qp   = vq + N;           // bf16 [b][s][64], pre-scaled by 0.25*log2(e)
  short* kq   = qp + N;           // bf16 fragment-major K-proj
  short* wqb3 = kq + N;           // frag-major bf16
  short* wkb3 = wqb3 + 4096;
  short* wt3  = wkb3 + 4096;      // frag-major bf16 [72 slabs][512]

  prep_lite<<<1040, 256, 0, stream>>>(v, wq, wk, conv_w,
                                      vq, wqb3, wkb3, wt3, out);
  qk_gemm_t<<<576, 256, 0, stream>>>(q, k, wt3, wqb3, wkb3,
                                     nq_w, nk_w, bq, bk, qp, kq);
  attn_flash<<<1152, 256, 0, stream>>>(qp, kq, vq, out);
}